// Round 7
// baseline (221.348 us; speedup 1.0000x reference)
//
#include <hip/hip_runtime.h>
#include <math.h>

#define NN 50000
#define NE 800000
#define ESLICE 100096   // 391 blocks * 256 threads; 8 slices cover NE

typedef __bf16 bf16x8 __attribute__((ext_vector_type(8)));
typedef __bf16 bf16x4 __attribute__((ext_vector_type(4)));
typedef float f32x4 __attribute__((ext_vector_type(4)));

__device__ __forceinline__ void gload16(const void* g, void* l){
  __builtin_amdgcn_global_load_lds((const __attribute__((address_space(1))) void*)g,
                                   (__attribute__((address_space(3))) void*)l, 16, 0, 0);
}

// ---------------- CSR build ----------------

__global__ void k_zero_i32(int* __restrict__ p, int n){
  int i = blockIdx.x * blockDim.x + threadIdx.x;
  if (i < n) p[i] = 0;
}

__global__ __launch_bounds__(256)
void k_rank(const int* __restrict__ erow, int* __restrict__ cnt, int* __restrict__ pos){
  const int t = blockIdx.x * 256 + threadIdx.x;
  #pragma unroll
  for (int k = 0; k < 8; ++k){
    const int e = t + k * ESLICE;
    if (e < NE){
      const int r = erow[e];
      pos[e] = atomicAdd(&cnt[r], 1);
    }
  }
}

__global__ __launch_bounds__(256)
void k_scan1(const int* __restrict__ cnt, int* __restrict__ rs, int* __restrict__ part, int n){
  const int t = threadIdx.x, b = blockIdx.x;
  const int i = b * 256 + t;
  int v = (i < n) ? cnt[i] : 0;
  const int lane = t & 63, w = t >> 6;
  int s = v;
  #pragma unroll
  for (int d = 1; d < 64; d <<= 1){ int u = __shfl_up(s, d); if (lane >= d) s += u; }
  __shared__ int wsum[4];
  if (lane == 63) wsum[w] = s;
  __syncthreads();
  int add = 0;
  #pragma unroll
  for (int k = 0; k < 4; ++k) if (k < w) add += wsum[k];
  s += add;
  if (i < n) rs[i + 1] = s;
  if (t == 255) part[b] = s;
}

__global__ __launch_bounds__(256)
void k_scan2(int* __restrict__ part, int nb){
  const int t = threadIdx.x;
  int v = (t < nb) ? part[t] : 0;
  const int lane = t & 63, w = t >> 6;
  int s = v;
  #pragma unroll
  for (int d = 1; d < 64; d <<= 1){ int u = __shfl_up(s, d); if (lane >= d) s += u; }
  __shared__ int wsum[4];
  if (lane == 63) wsum[w] = s;
  __syncthreads();
  int add = 0;
  #pragma unroll
  for (int k = 0; k < 4; ++k) if (k < w) add += wsum[k];
  s += add;
  if (t < nb) part[t] = s - v;
}

__global__ __launch_bounds__(256)
void k_scan3(int* __restrict__ rs, const int* __restrict__ part, int n){
  const int i = blockIdx.x * 256 + threadIdx.x;
  if (i < n) rs[i + 1] += part[blockIdx.x];
  if (i == 0) rs[0] = 0;
}

__global__ __launch_bounds__(256)
void k_scatter2(const int* __restrict__ erow, const int* __restrict__ ecol,
                const float* __restrict__ evalv, const int* __restrict__ rs,
                const int* __restrict__ pos, int2* __restrict__ out){
  const int t = blockIdx.x * 256 + threadIdx.x;
  #pragma unroll
  for (int k = 0; k < 8; ++k){
    const int e = t + k * ESLICE;
    if (e < NE){
      const int r = erow[e];
      const int p = rs[r] + pos[e];
      out[p] = make_int2(ecol[e], __float_as_int(evalv[e]));
    }
  }
}

// ---------------- W1 & W2 fp32 -> bf16 (one dispatch) ----------------
// blocks 0..79: W1 [256][300] -> W1b [256][320]; blocks 80..111: W2 [128][256] -> W2b.

__global__ __launch_bounds__(256)
void conv_w(const float* __restrict__ W1, const float* __restrict__ W2,
            __bf16* __restrict__ W1b, __bf16* __restrict__ W2b){
  const int b = blockIdx.x;
  const float* src; __bf16* dst; int q, K, Kp;
  if (b < 80){ src = W1; dst = W1b; q = b * 256 + threadIdx.x; K = 300; Kp = 320; }
  else       { src = W2; dst = W2b; q = (b - 80) * 256 + threadIdx.x; K = 256; Kp = 256; }
  const int perRow = Kp >> 2;
  const int r = q / perRow;
  const int k = (q - r * perRow) << 2;
  float4 v = make_float4(0.f, 0.f, 0.f, 0.f);
  if (k < K) v = *(const float4*)(src + (size_t)r * K + k);
  bf16x4 o;
  o[0] = (__bf16)v.x; o[1] = (__bf16)v.y; o[2] = (__bf16)v.z; o[3] = (__bf16)v.w;
  *(bf16x4*)(dst + (size_t)r * Kp + k) = o;
}

// ---------------- GEMM1: fp32 A (in-kernel cvt) x bf16 B^T -> bf16 C ----------------
// C[Mpad][N] = A32[M][300] * B[N][320]^T. BM=BN=128, BK=64, 4 waves 2x2,
// A reg-staged (float4 loads -> cvt -> swizzled ds_write), B via global_load_lds.

template<int KT, int KA>
__global__ __launch_bounds__(256)
void gemm_a32(const float* __restrict__ A32, const __bf16* __restrict__ B,
              __bf16* __restrict__ C, int M, int N, int ldB){
  __shared__ char ldsbuf[65536];                 // 2 x (16KB A + 16KB B)
  const int tid = threadIdx.x;
  const int lane = tid & 63;
  const int bn = blockIdx.x * 128;
  const int bm = blockIdx.y * 128;
  const int wr = (tid >> 7) & 1;
  const int wc = (tid >> 6) & 1;

  f32x4 acc[4][4];
  #pragma unroll
  for (int i = 0; i < 4; ++i)
    #pragma unroll
    for (int j = 0; j < 4; ++j) acc[i][j] = (f32x4){0.f, 0.f, 0.f, 0.f};

  // A: thread -> row r=tid>>1 (0..127), 32 floats at c0
  const int ar = tid >> 1;
  const int c0 = (tid & 1) * 32;
  const int sw = (ar & 7) << 4;

  auto stageA = [&](int kt, int sel){
    char* lb = ldsbuf + sel * 32768;
    float4 f[8];
    const int g = bm + ar;
    const float* src = A32 + (size_t)g * KA;
    #pragma unroll
    for (int q = 0; q < 8; ++q){
      const int gk = kt * 64 + c0 + q * 4;
      f[q] = (g < M && gk < KA) ? *(const float4*)(src + gk)
                                : make_float4(0.f, 0.f, 0.f, 0.f);
    }
    #pragma unroll
    for (int j = 0; j < 4; ++j){
      bf16x8 h;
      h[0] = (__bf16)f[2*j].x;   h[1] = (__bf16)f[2*j].y;
      h[2] = (__bf16)f[2*j].z;   h[3] = (__bf16)f[2*j].w;
      h[4] = (__bf16)f[2*j+1].x; h[5] = (__bf16)f[2*j+1].y;
      h[6] = (__bf16)f[2*j+1].z; h[7] = (__bf16)f[2*j+1].w;
      const int cb = c0 * 2 + j * 16;
      *(bf16x8*)(lb + ar * 128 + (cb ^ sw)) = h;
    }
  };

  auto stageB = [&](int kt, int sel){
    char* lb = ldsbuf + sel * 32768 + 16384;
    #pragma unroll
    for (int i = 0; i < 4; ++i){
      const int d = i * 4096 + tid * 16;
      const int row = d >> 7;
      const int colb = (d & 127) ^ ((row & 7) << 4);
      const __bf16* gp = B + (size_t)(bn + row) * ldB + kt * 64 + (colb >> 1);
      gload16(gp, lb + i * 4096 + (tid & 192) * 16);
    }
  };

  auto compute = [&](int sel){
    const char* lA = ldsbuf + sel * 32768;
    const char* lB = lA + 16384;
    #pragma unroll
    for (int c = 0; c < 2; ++c){
      bf16x8 av[4], bv[4];
      #pragma unroll
      for (int i = 0; i < 4; ++i){
        const int row = wr * 64 + i * 16 + (lane & 15);
        const int colb = (c * 64 + ((lane >> 4) << 4)) ^ ((row & 7) << 4);
        av[i] = *(const bf16x8*)(lA + row * 128 + colb);
      }
      #pragma unroll
      for (int j = 0; j < 4; ++j){
        const int row = wc * 64 + j * 16 + (lane & 15);
        const int colb = (c * 64 + ((lane >> 4) << 4)) ^ ((row & 7) << 4);
        bv[j] = *(const bf16x8*)(lB + row * 128 + colb);
      }
      #pragma unroll
      for (int i = 0; i < 4; ++i)
        #pragma unroll
        for (int j = 0; j < 4; ++j)
          acc[i][j] = __builtin_amdgcn_mfma_f32_16x16x32_bf16(av[i], bv[j], acc[i][j], 0, 0, 0);
    }
  };

  stageB(0, 0); stageA(0, 0);
  for (int kt = 0; kt < KT; ++kt){
    __syncthreads();
    if (kt + 1 < KT){ stageB(kt + 1, (kt + 1) & 1); stageA(kt + 1, (kt + 1) & 1); }
    compute(kt & 1);
  }

  // epilogue: acc -> LDS bf16 [128][136] -> coalesced bf16x8 stores
  __syncthreads();
  __bf16* lw = (__bf16*)ldsbuf;
  #pragma unroll
  for (int i = 0; i < 4; ++i)
    #pragma unroll
    for (int j = 0; j < 4; ++j)
      #pragma unroll
      for (int r = 0; r < 4; ++r){
        const int row = wr * 64 + i * 16 + ((lane >> 4) << 2) + r;
        const int col = wc * 64 + j * 16 + (lane & 15);
        lw[row * 136 + col] = (__bf16)acc[i][j][r];
      }
  __syncthreads();
  #pragma unroll
  for (int p = 0; p < 8; ++p){
    const int idx = p * 256 + tid;
    const int row = idx >> 4;
    const int c8 = (idx & 15) * 8;
    const bf16x8 o = *(const bf16x8*)&lw[row * 136 + c8];
    *(bf16x8*)(C + (size_t)(bm + row) * N + bn + c8) = o;
  }
}

// ---------------- GEMM2: bf16 x bf16^T -> bf16 (128x128 tile) ----------------

template<int KT>
__global__ __launch_bounds__(256)
void gemm_bf16(const __bf16* __restrict__ A, const __bf16* __restrict__ B,
               __bf16* __restrict__ C, int ld, int N){
  __shared__ char ldsbuf[65536];
  const int tid = threadIdx.x;
  const int lane = tid & 63;
  const int bn = blockIdx.x * 128;
  const int bm = blockIdx.y * 128;
  const int wr = (tid >> 7) & 1;
  const int wc = (tid >> 6) & 1;

  f32x4 acc[4][4];
  #pragma unroll
  for (int i = 0; i < 4; ++i)
    #pragma unroll
    for (int j = 0; j < 4; ++j) acc[i][j] = (f32x4){0.f, 0.f, 0.f, 0.f};

  auto stage = [&](int kt, int sel){
    char* lb = ldsbuf + sel * 32768;
    #pragma unroll
    for (int i = 0; i < 4; ++i){
      const int d = i * 4096 + tid * 16;
      const int row = d >> 7;
      const int colb = (d & 127) ^ ((row & 7) << 4);
      const __bf16* gp = A + (size_t)(bm + row) * ld + kt * 64 + (colb >> 1);
      gload16(gp, lb + i * 4096 + (tid & 192) * 16);
    }
    #pragma unroll
    for (int i = 0; i < 4; ++i){
      const int d = i * 4096 + tid * 16;
      const int row = d >> 7;
      const int colb = (d & 127) ^ ((row & 7) << 4);
      const __bf16* gp = B + (size_t)(bn + row) * ld + kt * 64 + (colb >> 1);
      gload16(gp, lb + 16384 + i * 4096 + (tid & 192) * 16);
    }
  };

  auto compute = [&](int sel){
    const char* lA = ldsbuf + sel * 32768;
    const char* lB = lA + 16384;
    #pragma unroll
    for (int c = 0; c < 2; ++c){
      bf16x8 av[4], bv[4];
      #pragma unroll
      for (int i = 0; i < 4; ++i){
        const int row = wr * 64 + i * 16 + (lane & 15);
        const int colb = (c * 64 + ((lane >> 4) << 4)) ^ ((row & 7) << 4);
        av[i] = *(const bf16x8*)(lA + row * 128 + colb);
      }
      #pragma unroll
      for (int j = 0; j < 4; ++j){
        const int row = wc * 64 + j * 16 + (lane & 15);
        const int colb = (c * 64 + ((lane >> 4) << 4)) ^ ((row & 7) << 4);
        bv[j] = *(const bf16x8*)(lB + row * 128 + colb);
      }
      #pragma unroll
      for (int i = 0; i < 4; ++i)
        #pragma unroll
        for (int j = 0; j < 4; ++j)
          acc[i][j] = __builtin_amdgcn_mfma_f32_16x16x32_bf16(av[i], bv[j], acc[i][j], 0, 0, 0);
    }
  };

  stage(0, 0);
  for (int kt = 0; kt < KT; ++kt){
    __syncthreads();
    if (kt + 1 < KT) stage(kt + 1, (kt + 1) & 1);
    compute(kt & 1);
  }

  __syncthreads();
  __bf16* lw = (__bf16*)ldsbuf;
  #pragma unroll
  for (int i = 0; i < 4; ++i)
    #pragma unroll
    for (int j = 0; j < 4; ++j)
      #pragma unroll
      for (int r = 0; r < 4; ++r){
        const int row = wr * 64 + i * 16 + ((lane >> 4) << 2) + r;
        const int col = wc * 64 + j * 16 + (lane & 15);
        lw[row * 136 + col] = (__bf16)acc[i][j][r];
      }
  __syncthreads();
  #pragma unroll
  for (int p = 0; p < 8; ++p){
    const int idx = p * 256 + tid;
    const int row = idx >> 4;
    const int c8 = (idx & 15) * 8;
    const bf16x8 o = *(const bf16x8*)&lw[row * 136 + c8];
    *(bf16x8*)(C + (size_t)(bm + row) * N + bn + c8) = o;
  }
}

// ---------------- SpMM (CSR, wave per row, 16-lane/edge quarters, x4 unroll) ----------------

__global__ __launch_bounds__(256)
void spmm_relu_half(const int2* __restrict__ ecv, const int* __restrict__ start,
                    const __bf16* __restrict__ H, const float* __restrict__ bias,
                    __bf16* __restrict__ out, int ch0){
  const int w = (blockIdx.x * 256 + threadIdx.x) >> 6;
  const int lane = threadIdx.x & 63;
  const int quar = lane >> 4, sl = lane & 15;
  if (w >= NN) return;
  const int s = start[w], e = start[w + 1];
  float a[8];
  #pragma unroll
  for (int k = 0; k < 8; ++k) a[k] = 0.f;
  for (int base = s; base < e; base += 64){
    int2 cv = make_int2(0, 0);
    if (base + lane < e) cv = ecv[base + lane];
    const int m = min(64, e - base);
    for (int j2 = 0; 16 * j2 < m; ++j2){
      int cc[4]; float vv[4];
      #pragma unroll
      for (int u = 0; u < 4; ++u){
        const int idx = 16 * j2 + quar + 4 * u;
        cc[u] = __shfl(cv.x, idx);
        vv[u] = __int_as_float(__shfl(cv.y, idx));
        if (idx >= m){ cc[u] = 0; vv[u] = 0.f; }
      }
      bf16x8 h[4];
      #pragma unroll
      for (int u = 0; u < 4; ++u)
        h[u] = *(const bf16x8*)(H + (size_t)cc[u] * 256 + ch0 + sl * 8);
      #pragma unroll
      for (int u = 0; u < 4; ++u)
        #pragma unroll
        for (int k = 0; k < 8; ++k) a[k] = fmaf(vv[u], (float)h[u][k], a[k]);
    }
  }
  #pragma unroll
  for (int k = 0; k < 8; ++k){
    a[k] += __shfl_xor(a[k], 32);
    a[k] += __shfl_xor(a[k], 16);
  }
  const float4 b0 = *(const float4*)(bias + ch0 + sl * 8);
  const float4 b1 = *(const float4*)(bias + ch0 + sl * 8 + 4);
  bf16x8 o;
  o[0] = (__bf16)fmaxf(a[0] + b0.x, 0.f);
  o[1] = (__bf16)fmaxf(a[1] + b0.y, 0.f);
  o[2] = (__bf16)fmaxf(a[2] + b0.z, 0.f);
  o[3] = (__bf16)fmaxf(a[3] + b0.w, 0.f);
  o[4] = (__bf16)fmaxf(a[4] + b1.x, 0.f);
  o[5] = (__bf16)fmaxf(a[5] + b1.y, 0.f);
  o[6] = (__bf16)fmaxf(a[6] + b1.z, 0.f);
  o[7] = (__bf16)fmaxf(a[7] + b1.w, 0.f);
  if (quar == 0) *(bf16x8*)(out + (size_t)w * 256 + ch0 + sl * 8) = o;
}

__global__ __launch_bounds__(256)
void spmm_bias_norm_b16(const int2* __restrict__ ecv, const int* __restrict__ start,
                        const __bf16* __restrict__ H, const float* __restrict__ bias,
                        float* __restrict__ out){
  const int w = (blockIdx.x * 256 + threadIdx.x) >> 6;
  const int lane = threadIdx.x & 63;
  const int quar = lane >> 4, sl = lane & 15;
  if (w >= NN) return;
  const int s = start[w], e = start[w + 1];
  float a[8];
  #pragma unroll
  for (int k = 0; k < 8; ++k) a[k] = 0.f;
  for (int base = s; base < e; base += 64){
    int2 cv = make_int2(0, 0);
    if (base + lane < e) cv = ecv[base + lane];
    const int m = min(64, e - base);
    for (int j2 = 0; 16 * j2 < m; ++j2){
      int cc[4]; float vv[4];
      #pragma unroll
      for (int u = 0; u < 4; ++u){
        const int idx = 16 * j2 + quar + 4 * u;
        cc[u] = __shfl(cv.x, idx);
        vv[u] = __int_as_float(__shfl(cv.y, idx));
        if (idx >= m){ cc[u] = 0; vv[u] = 0.f; }
      }
      bf16x8 h[4];
      #pragma unroll
      for (int u = 0; u < 4; ++u)
        h[u] = *(const bf16x8*)(H + (size_t)cc[u] * 128 + sl * 8);
      #pragma unroll
      for (int u = 0; u < 4; ++u)
        #pragma unroll
        for (int k = 0; k < 8; ++k) a[k] = fmaf(vv[u], (float)h[u][k], a[k]);
    }
  }
  #pragma unroll
  for (int k = 0; k < 8; ++k){
    a[k] += __shfl_xor(a[k], 32);
    a[k] += __shfl_xor(a[k], 16);
  }
  const float4 b0 = *(const float4*)(bias + sl * 8);
  const float4 b1 = *(const float4*)(bias + sl * 8 + 4);
  float f[8];
  f[0] = a[0] + b0.x; f[1] = a[1] + b0.y; f[2] = a[2] + b0.z; f[3] = a[3] + b0.w;
  f[4] = a[4] + b1.x; f[5] = a[5] + b1.y; f[6] = a[6] + b1.z; f[7] = a[7] + b1.w;
  float ss = 0.f;
  #pragma unroll
  for (int k = 0; k < 8; ++k) ss = fmaf(f[k], f[k], ss);
  #pragma unroll
  for (int m2 = 1; m2 < 16; m2 <<= 1) ss += __shfl_xor(ss, m2);
  const float inv = 1.f / fmaxf(sqrtf(ss), 1e-12f);
  if (quar == 0){
    float4 o0 = make_float4(f[0] * inv, f[1] * inv, f[2] * inv, f[3] * inv);
    float4 o1 = make_float4(f[4] * inv, f[5] * inv, f[6] * inv, f[7] * inv);
    *(float4*)(out + (size_t)w * 128 + sl * 8) = o0;
    *(float4*)(out + (size_t)w * 128 + sl * 8 + 4) = o1;
  }
}

// ---------------- launch ----------------
// ws layout (bytes):
//  W1b @ 0          [256][320] bf16  =    163,840
//  W2b @ 163840     [128][256] bf16  =     65,536
//  h1  @ 229376     [50048][256]bf16 = 25,624,576  (pos[800000] aliases head in CSR build)
//  h2  @ 25853952   [50048][256]bf16 = 25,624,576
//  h3  @ 51478528   [50048][128]bf16 = 12,812,288
//  ecv @ 64290816   800000 int2      =  6,400,000
//  rs  @ 70690816   50001 int        =    200,016
//  part@ 70890832   ~200 int
//  cur @ 70892416   50000 int        =    200,000   total ~71.1 MB

extern "C" void kernel_launch(void* const* d_in, const int* in_sizes, int n_in,
                              void* d_out, int out_size, void* d_ws, size_t ws_size,
                              hipStream_t stream){
  const float* x    = (const float*)d_in[0];
  const int*   erow = (const int*)d_in[1];
  const int*   ecol = (const int*)d_in[2];
  const float* evalv= (const float*)d_in[3];
  const float* W1   = (const float*)d_in[4];
  const float* b1   = (const float*)d_in[5];
  const float* W2   = (const float*)d_in[6];
  const float* b2   = (const float*)d_in[7];
  float* out = (float*)d_out;

  char* ws = (char*)d_ws;
  __bf16* W1b = (__bf16*)(ws);
  __bf16* W2b = (__bf16*)(ws + 163840);
  __bf16* h1  = (__bf16*)(ws + 229376);
  __bf16* h2  = (__bf16*)(ws + 25853952);
  __bf16* h3  = (__bf16*)(ws + 51478528);
  int2*   ecv = (int2*)(ws + 64290816);
  int*    rs  = (int*)(ws + 70690816);
  int*    part= (int*)(ws + 70890832);
  int*    cur = (int*)(ws + 70892416);
  int*    pos = (int*)(ws + 229376);     // aliases h1 head (dead until gemm1)

  // CSR build: rank(+hist) -> scan -> atomic-free scatter
  k_zero_i32<<<196, 256, 0, stream>>>(cur, NN);
  k_rank<<<391, 256, 0, stream>>>(erow, cur, pos);
  k_scan1<<<196, 256, 0, stream>>>(cur, rs, part, NN);
  k_scan2<<<1, 256, 0, stream>>>(part, 196);
  k_scan3<<<196, 256, 0, stream>>>(rs, part, NN);
  k_scatter2<<<391, 256, 0, stream>>>(erow, ecol, evalv, rs, pos, ecv);

  // weight conversions (one dispatch)
  conv_w<<<112, 256, 0, stream>>>(W1, W2, W1b, W2b);

  // layer 1: h1 = bf16(x @ W1^T) fused cvt; h2 = bf16(relu(A*h1 + b1)) in 2 halves
  gemm_a32<5, 300><<<dim3(2, 391), 256, 0, stream>>>(x, W1b, h1, NN, 256, 320);
  spmm_relu_half<<<12500, 256, 0, stream>>>(ecv, rs, h1, b1, h2, 0);
  spmm_relu_half<<<12500, 256, 0, stream>>>(ecv, rs, h1, b1, h2, 128);

  // layer 2: h3 = bf16(h2 @ W2b^T); out = l2norm(A*h3 + b2)
  gemm_bf16<4><<<dim3(1, 391), 256, 0, stream>>>(h2, W2b, h3, 256, 128);
  spmm_bias_norm_b16<<<12500, 256, 0, stream>>>(ecv, rs, h3, b2, out);
}